// Round 10
// baseline (425.695 us; speedup 1.0000x reference)
//
#include <hip/hip_runtime.h>
#include <math.h>

#define N_NODES 100000
#define N_EDGES 1600000
#define D 128
#define L_LAYERS 3
#define P_STATS 7
#define B_GRAPHS 64
#define BN_EPS 1e-5f
#define NEG_SLOPE 0.2f

#define NB 196        // buckets of 512 dst nodes
#define BCAP 10240
#define EPB 6400

typedef __attribute__((ext_vector_type(8))) short bf16x8;
typedef __attribute__((ext_vector_type(4))) float f32x4;

static __device__ __forceinline__ short f2bf(float f) {
    union { float f; unsigned u; } v;
    v.f = f;
    unsigned r = v.u + 0x7fffu + ((v.u >> 16) & 1u);  // RNE
    return (short)(r >> 16);
}

static __device__ __forceinline__ float bf2f(short s) {
    union { unsigned u; float f; } v;
    v.u = ((unsigned)(unsigned short)s) << 16;
    return v.f;
}

// ---------------- CSR build (bucketed) ----------------

__global__ void zero_n_kernel(int* __restrict__ p, int n) {
    int i = blockIdx.x * blockDim.x + threadIdx.x;
    if (i < n) p[i] = 0;
}

__global__ __launch_bounds__(256) void bucketA_kernel(const int* __restrict__ src,
                                                      const int* __restrict__ dst,
                                                      int* __restrict__ bucket_cnt,
                                                      int2* __restrict__ bucketbuf) {
    __shared__ int s_src[EPB];
    __shared__ int s_dst[EPB];
    __shared__ int hist[NB], base[NB], loc[NB];
    const int tid = threadIdx.x;
    const int e0 = blockIdx.x * EPB;
    for (int i = tid; i < NB; i += 256) { hist[i] = 0; loc[i] = 0; }
    __syncthreads();
    for (int i = tid; i < EPB; i += 256) {
        int s = src[e0 + i];
        int d = dst[e0 + i];
        s_src[i] = s;
        s_dst[i] = d;
        atomicAdd(&hist[d >> 9], 1);
    }
    __syncthreads();
    for (int i = tid; i < NB; i += 256)
        base[i] = hist[i] ? atomicAdd(&bucket_cnt[i], hist[i]) : 0;
    __syncthreads();
    for (int i = tid; i < EPB; i += 256) {
        int d = s_dst[i];
        int b = d >> 9;
        int off = atomicAdd(&loc[b], 1);
        int idx = base[b] + off;
        if (idx < BCAP) bucketbuf[(size_t)b * BCAP + idx] = make_int2(s_src[i], d);
    }
}

__global__ __launch_bounds__(256) void bucketB1_kernel(const int* __restrict__ bucket_cnt,
                                                       const int2* __restrict__ bucketbuf,
                                                       int* __restrict__ deg) {
    __shared__ int hist[512];
    const int b = blockIdx.x;
    for (int i = threadIdx.x; i < 512; i += 256) hist[i] = 0;
    __syncthreads();
    int cnt = min(bucket_cnt[b], BCAP);
    for (int i = threadIdx.x; i < cnt; i += 256) {
        int d = bucketbuf[(size_t)b * BCAP + i].y;
        atomicAdd(&hist[d & 511], 1);
    }
    __syncthreads();
    int nbase = b << 9;
    for (int i = threadIdx.x; i < 512; i += 256) {
        int node = nbase + i;
        if (node < N_NODES) deg[node] = hist[i];
    }
}

__global__ __launch_bounds__(256) void bucketB2_kernel(const int* __restrict__ bucket_cnt,
                                                       const int2* __restrict__ bucketbuf,
                                                       int* __restrict__ cursor,
                                                       int* __restrict__ csr_src) {
    const int b = blockIdx.x;
    int cnt = min(bucket_cnt[b], BCAP);
    for (int i = threadIdx.x; i < cnt; i += 256) {
        int2 p = bucketbuf[(size_t)b * BCAP + i];
        int pos = atomicAdd(&cursor[p.y], 1);
        csr_src[pos] = p.x;
    }
}

// ---------------- scans ----------------

__global__ void scan1_kernel(const int* __restrict__ deg, int* __restrict__ incl,
                             int* __restrict__ bsum) {
    __shared__ int s[256];
    const int tid = threadIdx.x;
    const int base = blockIdx.x * 2048;
    int v[8];
    int sum = 0;
    const int idx0 = base + tid * 8;
#pragma unroll
    for (int i = 0; i < 8; ++i) {
        int idx = idx0 + i;
        int d = (idx < N_NODES) ? deg[idx] : 0;
        sum += d;
        v[i] = sum;
    }
    s[tid] = sum;
    __syncthreads();
    for (int off = 1; off < 256; off <<= 1) {
        int t = (tid >= off) ? s[tid - off] : 0;
        __syncthreads();
        s[tid] += t;
        __syncthreads();
    }
    int prev = (tid > 0) ? s[tid - 1] : 0;
#pragma unroll
    for (int i = 0; i < 8; ++i) {
        int idx = idx0 + i;
        if (idx < N_NODES) incl[idx] = v[i] + prev;
    }
    if (tid == 255) bsum[blockIdx.x] = s[255];
}

__global__ void scan2_kernel(int* __restrict__ bsum, int nb) {
    if (threadIdx.x == 0 && blockIdx.x == 0) {
        int run = 0;
        for (int i = 0; i < nb; ++i) { int t = bsum[i]; bsum[i] = run; run += t; }
    }
}

__global__ void scan3_kernel(const int* __restrict__ deg, const int* __restrict__ incl,
                             const int* __restrict__ bsum, int* __restrict__ start,
                             int* __restrict__ cursor) {
    int i = blockIdx.x * blockDim.x + threadIdx.x;
    if (i < N_NODES) {
        int inc = incl[i] + bsum[i >> 11];
        int st = inc - deg[i];
        start[i] = st;
        cursor[i] = st;
    }
    if (i == 0) start[N_NODES] = N_EDGES;
}

// ---------------- per-graph stat projections ----------------
__global__ void gproj_kernel(const float* __restrict__ gs, const float* __restrict__ statWs,
                             const float* __restrict__ statBs, float* __restrict__ gproj) {
    int b = blockIdx.x;
    int l = blockIdx.y;
    int j = threadIdx.x;
    float acc = statBs[l * D + j];
#pragma unroll
    for (int p = 0; p < P_STATS; ++p) {
        float g = gs[b * P_STATS + p];
        if (g != g) g = -100.0f;
        acc += g * statWs[(l * P_STATS + p) * D + j];
    }
    gproj[(l * B_GRAPHS + b) * D + j] = acc;
}

// ---------------- weight convert: W[k][n] f32 -> Wt[n][k] bf16 ----------------
__global__ void wconv_kernel(const float* __restrict__ W1s, const float* __restrict__ W2s,
                             const float* __restrict__ fcW, short* __restrict__ wt) {
    int mid = blockIdx.y;
    const float* src = (mid < 3) ? (W1s + mid * D * D)
                                 : ((mid < 6) ? (W2s + (mid - 3) * D * D) : fcW);
    short* dstm = wt + mid * D * D;
    int i = blockIdx.x * 256 + threadIdx.x;
    int k = i >> 7, n = i & 127;
    dstm[n * D + k] = f2bf(src[i]);
}

// ---------------- x f32 -> bf16 ----------------
__global__ __launch_bounds__(256) void xconv_kernel(const float* __restrict__ x,
                                                    short* __restrict__ xb) {
    int i = blockIdx.x * 256 + threadIdx.x;
    const float4* x4 = (const float4*)x;
    float4 a = x4[i * 2], b = x4[i * 2 + 1];
    short s[8];
    s[0] = f2bf(a.x); s[1] = f2bf(a.y); s[2] = f2bf(a.z); s[3] = f2bf(a.w);
    s[4] = f2bf(b.x); s[5] = f2bf(b.y); s[6] = f2bf(b.z); s[7] = f2bf(b.w);
    *(bf16x8*)&xb[i * 8] = *(bf16x8*)s;
}

// ---------------- aggregation (round-5 proven config: 16 lanes/node, unroll-4) ----------------
__global__ __launch_bounds__(256) void agg_kernel(const short* __restrict__ hb,
                                                  const int* __restrict__ start,
                                                  const int* __restrict__ csr_src,
                                                  short* __restrict__ m_bf) {
    int node = blockIdx.x * 16 + (threadIdx.x >> 4);
    int c8 = threadIdx.x & 15;
    const bf16x8* h8 = (const bf16x8*)hb;

    bf16x8 own = h8[node * 16 + c8];
    float acc[8];
#pragma unroll
    for (int i = 0; i < 8; ++i) acc[i] = bf2f(own[i]);

    int s = start[node];
    int e = start[node + 1];
    int k = s;
    for (; k + 4 <= e; k += 4) {
        int sn0 = csr_src[k];
        int sn1 = csr_src[k + 1];
        int sn2 = csr_src[k + 2];
        int sn3 = csr_src[k + 3];
        bf16x8 v0 = h8[sn0 * 16 + c8];
        bf16x8 v1 = h8[sn1 * 16 + c8];
        bf16x8 v2 = h8[sn2 * 16 + c8];
        bf16x8 v3 = h8[sn3 * 16 + c8];
#pragma unroll
        for (int i = 0; i < 8; ++i) acc[i] += bf2f(v0[i]);
#pragma unroll
        for (int i = 0; i < 8; ++i) acc[i] += bf2f(v1[i]);
#pragma unroll
        for (int i = 0; i < 8; ++i) acc[i] += bf2f(v2[i]);
#pragma unroll
        for (int i = 0; i < 8; ++i) acc[i] += bf2f(v3[i]);
    }
    for (; k < e; ++k) {
        int sn0 = csr_src[k];
        bf16x8 v0 = h8[sn0 * 16 + c8];
#pragma unroll
        for (int i = 0; i < 8; ++i) acc[i] += bf2f(v0[i]);
    }

    short pk[8];
#pragma unroll
    for (int i = 0; i < 8; ++i) pk[i] = f2bf(acc[i]);
    *(bf16x8*)&m_bf[node * D + c8 * 8] = *(bf16x8*)pk;
}

// ---------------- MFMA MLP (GEMM-only, 64-node tile, high occupancy) ----------------
// Block: 64 nodes x 128 features, 256 threads = 4 waves (2 node-halves x 2 feat-halves).
// __launch_bounds__(256,6): 6 blocks/CU (LDS 17KB allows 9), VGPR cap 85 keeps the
// per-kt staged W/m fragments in registers without spill.
template <bool FUSE_FC>
__global__ __launch_bounds__(256, 6) void mlp_mfma_kernel(
    const short* __restrict__ m_bf,
    const short* __restrict__ W1t,
    const float* __restrict__ b1,
    const float* __restrict__ gamma, const float* __restrict__ beta,
    const float* __restrict__ mean, const float* __restrict__ var,
    const short* __restrict__ W2t,
    const float* __restrict__ b2,
    const float* __restrict__ gproj, const int* __restrict__ batch,
    const short* __restrict__ Wft, const float* __restrict__ fcb,
    float* __restrict__ outf, short* __restrict__ outb) {
    __shared__ short sy[64 * 128];  // 16KB, XOR-swizzled rows
    __shared__ float sB1[128], sSc[128], sSb[128], sB2[128], sFC[128];

    const int tid = threadIdx.x;
    const int wid = tid >> 6;
    const int lane = tid & 63;
    const int lr = lane & 15;
    const int lk = lane >> 4;

    if (tid < 128) {
        sB1[tid] = b1[tid];
        float sc = gamma[tid] * rsqrtf(var[tid] + BN_EPS);
        sSc[tid] = sc;
        sSb[tid] = beta[tid] - mean[tid] * sc;
        sB2[tid] = b2[tid];
        if (FUSE_FC) sFC[tid] = fcb[tid];
    }
    __syncthreads();

    const int nlBase = (wid >> 1) * 32;              // node-local base (0 or 32)
    const int nodeBase = blockIdx.x * 64 + nlBase;
    const int featBase = (wid & 1) * 64;

    int nIdx[2];
#pragma unroll
    for (int mt = 0; mt < 2; ++mt) {
        int n = nodeBase + mt * 16 + lr;
        nIdx[mt] = (n < N_NODES) ? n : (N_NODES - 1);
    }

    f32x4 acc[4][2];
#pragma unroll
    for (int ft = 0; ft < 4; ++ft)
#pragma unroll
        for (int mt = 0; mt < 2; ++mt)
            acc[ft][mt] = (f32x4)(0.0f);

    // ---- GEMM1 (m streamed from global, per-kt staged fragments) ----
#pragma unroll
    for (int kt = 0; kt < 4; ++kt) {
        bf16x8 wfk[4];
#pragma unroll
        for (int ft = 0; ft < 4; ++ft)
            wfk[ft] = *(const bf16x8*)&W1t[(featBase + ft * 16 + lr) * D + kt * 32 + lk * 8];
        bf16x8 mf[2];
#pragma unroll
        for (int mt = 0; mt < 2; ++mt)
            mf[mt] = *(const bf16x8*)&m_bf[nIdx[mt] * D + kt * 32 + lk * 8];
#pragma unroll
        for (int ft = 0; ft < 4; ++ft)
#pragma unroll
            for (int mt = 0; mt < 2; ++mt)
                acc[ft][mt] = __builtin_amdgcn_mfma_f32_16x16x32_bf16(wfk[ft], mf[mt],
                                                                      acc[ft][mt], 0, 0, 0);
    }

    // ---- bias + LeakyReLU + BN -> bf16 -> LDS (swizzled) ----
#pragma unroll
    for (int ft = 0; ft < 4; ++ft) {
        int f0 = featBase + ft * 16 + lk * 4;
#pragma unroll
        for (int mt = 0; mt < 2; ++mt) {
            int nl = nlBase + mt * 16 + lr;
            short4 pk;
#pragma unroll
            for (int r = 0; r < 4; ++r) {
                float v = acc[ft][mt][r] + sB1[f0 + r];
                v = (v > 0.f) ? v : NEG_SLOPE * v;
                v = v * sSc[f0 + r] + sSb[f0 + r];
                ((short*)&pk)[r] = f2bf(v);
            }
            int byteoff = nl * 256 + f0 * 2;
            byteoff ^= (nl & 7) << 4;
            *(short4*)((char*)sy + byteoff) = pk;
        }
    }
    __syncthreads();

    // ---- GEMM2 ----
#pragma unroll
    for (int ft = 0; ft < 4; ++ft)
#pragma unroll
        for (int mt = 0; mt < 2; ++mt)
            acc[ft][mt] = (f32x4)(0.0f);

#pragma unroll
    for (int kt = 0; kt < 4; ++kt) {
        bf16x8 wfk[4];
#pragma unroll
        for (int ft = 0; ft < 4; ++ft)
            wfk[ft] = *(const bf16x8*)&W2t[(featBase + ft * 16 + lr) * D + kt * 32 + lk * 8];
        bf16x8 yf[2];
#pragma unroll
        for (int mt = 0; mt < 2; ++mt) {
            int nl = nlBase + mt * 16 + lr;
            int byteoff = nl * 256 + kt * 64 + lk * 16;
            byteoff ^= (nl & 7) << 4;
            yf[mt] = *(const bf16x8*)((char*)sy + byteoff);
        }
#pragma unroll
        for (int ft = 0; ft < 4; ++ft)
#pragma unroll
            for (int mt = 0; mt < 2; ++mt)
                acc[ft][mt] = __builtin_amdgcn_mfma_f32_16x16x32_bf16(wfk[ft], yf[mt],
                                                                      acc[ft][mt], 0, 0, 0);
    }

    if (!FUSE_FC) {
        // ---- bias + LeakyReLU + gproj add -> bf16 store ----
#pragma unroll
        for (int mt = 0; mt < 2; ++mt) {
            int node = nodeBase + mt * 16 + lr;
            if (node >= N_NODES) continue;
            int bid = batch[node];
#pragma unroll
            for (int ft = 0; ft < 4; ++ft) {
                int f0 = featBase + ft * 16 + lk * 4;
                const float4 gp = *(const float4*)&gproj[bid * D + f0];
                float v0 = acc[ft][mt][0] + sB2[f0 + 0]; v0 = (v0 > 0.f) ? v0 : NEG_SLOPE * v0; v0 += gp.x;
                float v1 = acc[ft][mt][1] + sB2[f0 + 1]; v1 = (v1 > 0.f) ? v1 : NEG_SLOPE * v1; v1 += gp.y;
                float v2 = acc[ft][mt][2] + sB2[f0 + 2]; v2 = (v2 > 0.f) ? v2 : NEG_SLOPE * v2; v2 += gp.z;
                float v3 = acc[ft][mt][3] + sB2[f0 + 3]; v3 = (v3 > 0.f) ? v3 : NEG_SLOPE * v3; v3 += gp.w;
                short4 pk;
                pk.x = f2bf(v0); pk.y = f2bf(v1); pk.z = f2bf(v2); pk.w = f2bf(v3);
                *(short4*)&outb[node * D + f0] = pk;
            }
        }
        return;
    }

    // ---- FUSE_FC: h -> LDS (swizzled), then GEMM3 with fcW ----
    __syncthreads();  // all waves done reading sy in GEMM2 before overwrite
#pragma unroll
    for (int ft = 0; ft < 4; ++ft) {
        int f0 = featBase + ft * 16 + lk * 4;
#pragma unroll
        for (int mt = 0; mt < 2; ++mt) {
            int nl = nlBase + mt * 16 + lr;
            int bid = batch[nIdx[mt]];
            const float4 gp = *(const float4*)&gproj[bid * D + f0];
            short4 pk;
            float v0 = acc[ft][mt][0] + sB2[f0 + 0]; v0 = (v0 > 0.f) ? v0 : NEG_SLOPE * v0; v0 += gp.x;
            float v1 = acc[ft][mt][1] + sB2[f0 + 1]; v1 = (v1 > 0.f) ? v1 : NEG_SLOPE * v1; v1 += gp.y;
            float v2 = acc[ft][mt][2] + sB2[f0 + 2]; v2 = (v2 > 0.f) ? v2 : NEG_SLOPE * v2; v2 += gp.z;
            float v3 = acc[ft][mt][3] + sB2[f0 + 3]; v3 = (v3 > 0.f) ? v3 : NEG_SLOPE * v3; v3 += gp.w;
            pk.x = f2bf(v0); pk.y = f2bf(v1); pk.z = f2bf(v2); pk.w = f2bf(v3);
            int byteoff = nl * 256 + f0 * 2;
            byteoff ^= (nl & 7) << 4;
            *(short4*)((char*)sy + byteoff) = pk;
        }
    }
    __syncthreads();

#pragma unroll
    for (int ft = 0; ft < 4; ++ft)
#pragma unroll
        for (int mt = 0; mt < 2; ++mt)
            acc[ft][mt] = (f32x4)(0.0f);

#pragma unroll
    for (int kt = 0; kt < 4; ++kt) {
        bf16x8 wfk[4];
#pragma unroll
        for (int ft = 0; ft < 4; ++ft)
            wfk[ft] = *(const bf16x8*)&Wft[(featBase + ft * 16 + lr) * D + kt * 32 + lk * 8];
        bf16x8 hf[2];
#pragma unroll
        for (int mt = 0; mt < 2; ++mt) {
            int nl = nlBase + mt * 16 + lr;
            int byteoff = nl * 256 + kt * 64 + lk * 16;
            byteoff ^= (nl & 7) << 4;
            hf[mt] = *(const bf16x8*)((char*)sy + byteoff);
        }
#pragma unroll
        for (int ft = 0; ft < 4; ++ft)
#pragma unroll
            for (int mt = 0; mt < 2; ++mt)
                acc[ft][mt] = __builtin_amdgcn_mfma_f32_16x16x32_bf16(wfk[ft], hf[mt],
                                                                      acc[ft][mt], 0, 0, 0);
    }

#pragma unroll
    for (int mt = 0; mt < 2; ++mt) {
        int node = nodeBase + mt * 16 + lr;
        if (node >= N_NODES) continue;
#pragma unroll
        for (int ft = 0; ft < 4; ++ft) {
            int f0 = featBase + ft * 16 + lk * 4;
            float4 o;
            o.x = acc[ft][mt][0] + sFC[f0 + 0];
            o.y = acc[ft][mt][1] + sFC[f0 + 1];
            o.z = acc[ft][mt][2] + sFC[f0 + 2];
            o.w = acc[ft][mt][3] + sFC[f0 + 3];
            *(float4*)&outf[node * D + f0] = o;
        }
    }
}

// ---------------- launch ----------------

extern "C" void kernel_launch(void* const* d_in, const int* in_sizes, int n_in,
                              void* d_out, int out_size, void* d_ws, size_t ws_size,
                              hipStream_t stream) {
    const float* x = (const float*)d_in[0];
    const int* ei = (const int*)d_in[1];
    const int* src = ei;
    const int* dst = ei + N_EDGES;
    const int* batch = (const int*)d_in[2];
    const float* gs = (const float*)d_in[3];
    const float* W1s = (const float*)d_in[4];
    const float* b1s = (const float*)d_in[5];
    const float* gammas = (const float*)d_in[6];
    const float* betas = (const float*)d_in[7];
    const float* means = (const float*)d_in[8];
    const float* vars = (const float*)d_in[9];
    const float* W2s = (const float*)d_in[10];
    const float* b2s = (const float*)d_in[11];
    const float* statWs = (const float*)d_in[12];
    const float* statBs = (const float*)d_in[13];
    const float* fcW = (const float*)d_in[14];
    const float* fcB = (const float*)d_in[15];
    float* out = (float*)d_out;

    char* ws = (char*)d_ws;
    auto alloc = [&](size_t bytes) {
        char* p = ws;
        ws += (bytes + 255) / 256 * 256;
        return p;
    };
    int* deg = (int*)alloc(N_NODES * sizeof(int));
    int* incl = (int*)alloc(N_NODES * sizeof(int));
    int* bsum = (int*)alloc(64 * sizeof(int));
    int* start = (int*)alloc((N_NODES + 1) * sizeof(int));
    int* cursor = (int*)alloc(N_NODES * sizeof(int));
    int* csr_src = (int*)alloc(N_EDGES * sizeof(int));
    int* bucket_cnt = (int*)alloc(NB * sizeof(int));
    int2* bucketbuf = (int2*)alloc((size_t)NB * BCAP * sizeof(int2));
    float* gproj = (float*)alloc((size_t)L_LAYERS * B_GRAPHS * D * sizeof(float));
    short* wt = (short*)alloc((size_t)7 * D * D * sizeof(short));
    short* xb = (short*)alloc((size_t)N_NODES * D * sizeof(short));
    short* hb = (short*)alloc((size_t)N_NODES * D * sizeof(short));
    short* m_bf = (short*)alloc((size_t)N_NODES * D * sizeof(short));

    const int nscan = (N_NODES + 2047) / 2048;

    // CSR build, bucketed
    zero_n_kernel<<<1, 256, 0, stream>>>(bucket_cnt, NB);
    bucketA_kernel<<<N_EDGES / EPB, 256, 0, stream>>>(src, dst, bucket_cnt, bucketbuf);
    bucketB1_kernel<<<NB, 256, 0, stream>>>(bucket_cnt, bucketbuf, deg);
    scan1_kernel<<<nscan, 256, 0, stream>>>(deg, incl, bsum);
    scan2_kernel<<<1, 64, 0, stream>>>(bsum, nscan);
    scan3_kernel<<<(N_NODES + 255) / 256, 256, 0, stream>>>(deg, incl, bsum, start, cursor);
    bucketB2_kernel<<<NB, 256, 0, stream>>>(bucket_cnt, bucketbuf, cursor, csr_src);

    gproj_kernel<<<dim3(B_GRAPHS, L_LAYERS), D, 0, stream>>>(gs, statWs, statBs, gproj);
    wconv_kernel<<<dim3(64, 7), 256, 0, stream>>>(W1s, W2s, fcW, wt);
    xconv_kernel<<<(N_NODES * D / 8 + 255) / 256, 256, 0, stream>>>(x, xb);

    const int agg_blocks = N_NODES / 16;         // 6250
    const int mlp_blocks = (N_NODES + 63) / 64;  // 1563

    // layer 0
    agg_kernel<<<agg_blocks, 256, 0, stream>>>(xb, start, csr_src, m_bf);
    mlp_mfma_kernel<false><<<mlp_blocks, 256, 0, stream>>>(
        m_bf, wt + 0 * D * D, b1s + 0 * D, gammas + 0 * D, betas + 0 * D, means + 0 * D,
        vars + 0 * D, wt + 3 * D * D, b2s + 0 * D, gproj + 0 * B_GRAPHS * D, batch,
        nullptr, nullptr, nullptr, hb);
    // layer 1
    agg_kernel<<<agg_blocks, 256, 0, stream>>>(hb, start, csr_src, m_bf);
    mlp_mfma_kernel<false><<<mlp_blocks, 256, 0, stream>>>(
        m_bf, wt + 1 * D * D, b1s + 1 * D, gammas + 1 * D, betas + 1 * D, means + 1 * D,
        vars + 1 * D, wt + 4 * D * D, b2s + 1 * D, gproj + 1 * B_GRAPHS * D, batch,
        nullptr, nullptr, nullptr, hb);
    // layer 2
    agg_kernel<<<agg_blocks, 256, 0, stream>>>(hb, start, csr_src, m_bf);
    mlp_mfma_kernel<true><<<mlp_blocks, 256, 0, stream>>>(
        m_bf, wt + 2 * D * D, b1s + 2 * D, gammas + 2 * D, betas + 2 * D, means + 2 * D,
        vars + 2 * D, wt + 5 * D * D, b2s + 2 * D, gproj + 2 * B_GRAPHS * D, batch,
        wt + 6 * D * D, fcB, out, nullptr);
}

// Round 11
// 412.541 us; speedup vs baseline: 1.0319x; 1.0319x over previous
//
#include <hip/hip_runtime.h>
#include <math.h>

#define N_NODES 100000
#define N_EDGES 1600000
#define D 128
#define L_LAYERS 3
#define P_STATS 7
#define B_GRAPHS 64
#define BN_EPS 1e-5f
#define NEG_SLOPE 0.2f

#define NB 196        // buckets of 512 dst nodes
#define BCAP 10240
#define EPB 6400

typedef __attribute__((ext_vector_type(8))) short bf16x8;
typedef __attribute__((ext_vector_type(4))) float f32x4;

static __device__ __forceinline__ short f2bf(float f) {
    union { float f; unsigned u; } v;
    v.f = f;
    unsigned r = v.u + 0x7fffu + ((v.u >> 16) & 1u);  // RNE
    return (short)(r >> 16);
}

static __device__ __forceinline__ float bf2f(short s) {
    union { unsigned u; float f; } v;
    v.u = ((unsigned)(unsigned short)s) << 16;
    return v.f;
}

// ---------------- CSR build (bucketed) ----------------

__global__ void zero_n_kernel(int* __restrict__ p, int n) {
    int i = blockIdx.x * blockDim.x + threadIdx.x;
    if (i < n) p[i] = 0;
}

__global__ __launch_bounds__(256) void bucketA_kernel(const int* __restrict__ src,
                                                      const int* __restrict__ dst,
                                                      int* __restrict__ bucket_cnt,
                                                      int2* __restrict__ bucketbuf) {
    __shared__ int s_src[EPB];
    __shared__ int s_dst[EPB];
    __shared__ int hist[NB], base[NB], loc[NB];
    const int tid = threadIdx.x;
    const int e0 = blockIdx.x * EPB;
    for (int i = tid; i < NB; i += 256) { hist[i] = 0; loc[i] = 0; }
    __syncthreads();
    for (int i = tid; i < EPB; i += 256) {
        int s = src[e0 + i];
        int d = dst[e0 + i];
        s_src[i] = s;
        s_dst[i] = d;
        atomicAdd(&hist[d >> 9], 1);
    }
    __syncthreads();
    for (int i = tid; i < NB; i += 256)
        base[i] = hist[i] ? atomicAdd(&bucket_cnt[i], hist[i]) : 0;
    __syncthreads();
    for (int i = tid; i < EPB; i += 256) {
        int d = s_dst[i];
        int b = d >> 9;
        int off = atomicAdd(&loc[b], 1);
        int idx = base[b] + off;
        if (idx < BCAP) bucketbuf[(size_t)b * BCAP + idx] = make_int2(s_src[i], d);
    }
}

__global__ __launch_bounds__(256) void bucketB1_kernel(const int* __restrict__ bucket_cnt,
                                                       const int2* __restrict__ bucketbuf,
                                                       int* __restrict__ deg) {
    __shared__ int hist[512];
    const int b = blockIdx.x;
    for (int i = threadIdx.x; i < 512; i += 256) hist[i] = 0;
    __syncthreads();
    int cnt = min(bucket_cnt[b], BCAP);
    for (int i = threadIdx.x; i < cnt; i += 256) {
        int d = bucketbuf[(size_t)b * BCAP + i].y;
        atomicAdd(&hist[d & 511], 1);
    }
    __syncthreads();
    int nbase = b << 9;
    for (int i = threadIdx.x; i < 512; i += 256) {
        int node = nbase + i;
        if (node < N_NODES) deg[node] = hist[i];
    }
}

__global__ __launch_bounds__(256) void bucketB2_kernel(const int* __restrict__ bucket_cnt,
                                                       const int2* __restrict__ bucketbuf,
                                                       int* __restrict__ cursor,
                                                       int* __restrict__ csr_src) {
    const int b = blockIdx.x;
    int cnt = min(bucket_cnt[b], BCAP);
    for (int i = threadIdx.x; i < cnt; i += 256) {
        int2 p = bucketbuf[(size_t)b * BCAP + i];
        int pos = atomicAdd(&cursor[p.y], 1);
        csr_src[pos] = p.x;
    }
}

// ---------------- scans ----------------

__global__ void scan1_kernel(const int* __restrict__ deg, int* __restrict__ incl,
                             int* __restrict__ bsum) {
    __shared__ int s[256];
    const int tid = threadIdx.x;
    const int base = blockIdx.x * 2048;
    int v[8];
    int sum = 0;
    const int idx0 = base + tid * 8;
#pragma unroll
    for (int i = 0; i < 8; ++i) {
        int idx = idx0 + i;
        int d = (idx < N_NODES) ? deg[idx] : 0;
        sum += d;
        v[i] = sum;
    }
    s[tid] = sum;
    __syncthreads();
    for (int off = 1; off < 256; off <<= 1) {
        int t = (tid >= off) ? s[tid - off] : 0;
        __syncthreads();
        s[tid] += t;
        __syncthreads();
    }
    int prev = (tid > 0) ? s[tid - 1] : 0;
#pragma unroll
    for (int i = 0; i < 8; ++i) {
        int idx = idx0 + i;
        if (idx < N_NODES) incl[idx] = v[i] + prev;
    }
    if (tid == 255) bsum[blockIdx.x] = s[255];
}

__global__ void scan2_kernel(int* __restrict__ bsum, int nb) {
    if (threadIdx.x == 0 && blockIdx.x == 0) {
        int run = 0;
        for (int i = 0; i < nb; ++i) { int t = bsum[i]; bsum[i] = run; run += t; }
    }
}

__global__ void scan3_kernel(const int* __restrict__ deg, const int* __restrict__ incl,
                             const int* __restrict__ bsum, int* __restrict__ start,
                             int* __restrict__ cursor) {
    int i = blockIdx.x * blockDim.x + threadIdx.x;
    if (i < N_NODES) {
        int inc = incl[i] + bsum[i >> 11];
        int st = inc - deg[i];
        start[i] = st;
        cursor[i] = st;
    }
    if (i == 0) start[N_NODES] = N_EDGES;
}

// ---------------- per-graph stat projections ----------------
__global__ void gproj_kernel(const float* __restrict__ gs, const float* __restrict__ statWs,
                             const float* __restrict__ statBs, float* __restrict__ gproj) {
    int b = blockIdx.x;
    int l = blockIdx.y;
    int j = threadIdx.x;
    float acc = statBs[l * D + j];
#pragma unroll
    for (int p = 0; p < P_STATS; ++p) {
        float g = gs[b * P_STATS + p];
        if (g != g) g = -100.0f;
        acc += g * statWs[(l * P_STATS + p) * D + j];
    }
    gproj[(l * B_GRAPHS + b) * D + j] = acc;
}

// ---------------- weight convert: W[k][n] f32 -> Wt[n][k] bf16 ----------------
__global__ void wconv_kernel(const float* __restrict__ W1s, const float* __restrict__ W2s,
                             const float* __restrict__ fcW, short* __restrict__ wt) {
    int mid = blockIdx.y;
    const float* src = (mid < 3) ? (W1s + mid * D * D)
                                 : ((mid < 6) ? (W2s + (mid - 3) * D * D) : fcW);
    short* dstm = wt + mid * D * D;
    int i = blockIdx.x * 256 + threadIdx.x;
    int k = i >> 7, n = i & 127;
    dstm[n * D + k] = f2bf(src[i]);
}

// ---------------- x f32 -> bf16 ----------------
__global__ __launch_bounds__(256) void xconv_kernel(const float* __restrict__ x,
                                                    short* __restrict__ xb) {
    int i = blockIdx.x * 256 + threadIdx.x;
    const float4* x4 = (const float4*)x;
    float4 a = x4[i * 2], b = x4[i * 2 + 1];
    short s[8];
    s[0] = f2bf(a.x); s[1] = f2bf(a.y); s[2] = f2bf(a.z); s[3] = f2bf(a.w);
    s[4] = f2bf(b.x); s[5] = f2bf(b.y); s[6] = f2bf(b.z); s[7] = f2bf(b.w);
    *(bf16x8*)&xb[i * 8] = *(bf16x8*)s;
}

// ---------------- aggregation (proven config: 16 lanes/node, unroll-4) ----------------
__global__ __launch_bounds__(256) void agg_kernel(const short* __restrict__ hb,
                                                  const int* __restrict__ start,
                                                  const int* __restrict__ csr_src,
                                                  short* __restrict__ m_bf) {
    int node = blockIdx.x * 16 + (threadIdx.x >> 4);
    int c8 = threadIdx.x & 15;
    const bf16x8* h8 = (const bf16x8*)hb;

    bf16x8 own = h8[node * 16 + c8];
    float acc[8];
#pragma unroll
    for (int i = 0; i < 8; ++i) acc[i] = bf2f(own[i]);

    int s = start[node];
    int e = start[node + 1];
    int k = s;
    for (; k + 4 <= e; k += 4) {
        int sn0 = csr_src[k];
        int sn1 = csr_src[k + 1];
        int sn2 = csr_src[k + 2];
        int sn3 = csr_src[k + 3];
        bf16x8 v0 = h8[sn0 * 16 + c8];
        bf16x8 v1 = h8[sn1 * 16 + c8];
        bf16x8 v2 = h8[sn2 * 16 + c8];
        bf16x8 v3 = h8[sn3 * 16 + c8];
#pragma unroll
        for (int i = 0; i < 8; ++i) acc[i] += bf2f(v0[i]);
#pragma unroll
        for (int i = 0; i < 8; ++i) acc[i] += bf2f(v1[i]);
#pragma unroll
        for (int i = 0; i < 8; ++i) acc[i] += bf2f(v2[i]);
#pragma unroll
        for (int i = 0; i < 8; ++i) acc[i] += bf2f(v3[i]);
    }
    for (; k < e; ++k) {
        int sn0 = csr_src[k];
        bf16x8 v0 = h8[sn0 * 16 + c8];
#pragma unroll
        for (int i = 0; i < 8; ++i) acc[i] += bf2f(v0[i]);
    }

    short pk[8];
#pragma unroll
    for (int i = 0; i < 8; ++i) pk[i] = f2bf(acc[i]);
    *(bf16x8*)&m_bf[node * D + c8 * 8] = *(bf16x8*)pk;
}

// ---------------- MFMA MLP (GEMM-only, 64-node tile, (256,4)) ----------------
// Block: 64 nodes x 128 features, 256 threads = 4 waves (2 node-halves x 2 feat-halves).
// (256,4): VGPR cap 128 -> compiler picks ~52-72, keeping staged fragments in flight
// (the (256,6)->40-VGPR serialization of rounds 7/10); 18.9KB LDS allows 8 blocks/CU.
// Non-FC epilogue stages h through LDS for fully-coalesced 256B-row stores
// (direct 8B scatter stores measured 2.6x write amplification: 67MB vs 25.6MB).
template <bool FUSE_FC>
__global__ __launch_bounds__(256, 4) void mlp_mfma_kernel(
    const short* __restrict__ m_bf,
    const short* __restrict__ W1t,
    const float* __restrict__ b1,
    const float* __restrict__ gamma, const float* __restrict__ beta,
    const float* __restrict__ mean, const float* __restrict__ var,
    const short* __restrict__ W2t,
    const float* __restrict__ b2,
    const float* __restrict__ gproj, const int* __restrict__ batch,
    const short* __restrict__ Wft, const float* __restrict__ fcb,
    float* __restrict__ outf, short* __restrict__ outb) {
    __shared__ short sy[64 * 128];  // 16KB, XOR-swizzled rows
    __shared__ float sB1[128], sSc[128], sSb[128], sB2[128], sFC[128];

    const int tid = threadIdx.x;
    const int wid = tid >> 6;
    const int lane = tid & 63;
    const int lr = lane & 15;
    const int lk = lane >> 4;

    if (tid < 128) {
        sB1[tid] = b1[tid];
        float sc = gamma[tid] * rsqrtf(var[tid] + BN_EPS);
        sSc[tid] = sc;
        sSb[tid] = beta[tid] - mean[tid] * sc;
        sB2[tid] = b2[tid];
        if (FUSE_FC) sFC[tid] = fcb[tid];
    }
    __syncthreads();

    const int nlBase = (wid >> 1) * 32;              // node-local base (0 or 32)
    const int nodeBase = blockIdx.x * 64 + nlBase;
    const int featBase = (wid & 1) * 64;

    int nIdx[2];
#pragma unroll
    for (int mt = 0; mt < 2; ++mt) {
        int n = nodeBase + mt * 16 + lr;
        nIdx[mt] = (n < N_NODES) ? n : (N_NODES - 1);
    }

    f32x4 acc[4][2];
#pragma unroll
    for (int ft = 0; ft < 4; ++ft)
#pragma unroll
        for (int mt = 0; mt < 2; ++mt)
            acc[ft][mt] = (f32x4)(0.0f);

    // ---- GEMM1 (m streamed from global, per-kt staged fragments) ----
#pragma unroll
    for (int kt = 0; kt < 4; ++kt) {
        bf16x8 wfk[4];
#pragma unroll
        for (int ft = 0; ft < 4; ++ft)
            wfk[ft] = *(const bf16x8*)&W1t[(featBase + ft * 16 + lr) * D + kt * 32 + lk * 8];
        bf16x8 mf[2];
#pragma unroll
        for (int mt = 0; mt < 2; ++mt)
            mf[mt] = *(const bf16x8*)&m_bf[nIdx[mt] * D + kt * 32 + lk * 8];
#pragma unroll
        for (int ft = 0; ft < 4; ++ft)
#pragma unroll
            for (int mt = 0; mt < 2; ++mt)
                acc[ft][mt] = __builtin_amdgcn_mfma_f32_16x16x32_bf16(wfk[ft], mf[mt],
                                                                      acc[ft][mt], 0, 0, 0);
    }

    // ---- bias + LeakyReLU + BN -> bf16 -> LDS (swizzled) ----
#pragma unroll
    for (int ft = 0; ft < 4; ++ft) {
        int f0 = featBase + ft * 16 + lk * 4;
#pragma unroll
        for (int mt = 0; mt < 2; ++mt) {
            int nl = nlBase + mt * 16 + lr;
            short4 pk;
#pragma unroll
            for (int r = 0; r < 4; ++r) {
                float v = acc[ft][mt][r] + sB1[f0 + r];
                v = (v > 0.f) ? v : NEG_SLOPE * v;
                v = v * sSc[f0 + r] + sSb[f0 + r];
                ((short*)&pk)[r] = f2bf(v);
            }
            int byteoff = nl * 256 + f0 * 2;
            byteoff ^= (nl & 7) << 4;
            *(short4*)((char*)sy + byteoff) = pk;
        }
    }
    __syncthreads();

    // ---- GEMM2 ----
#pragma unroll
    for (int ft = 0; ft < 4; ++ft)
#pragma unroll
        for (int mt = 0; mt < 2; ++mt)
            acc[ft][mt] = (f32x4)(0.0f);

#pragma unroll
    for (int kt = 0; kt < 4; ++kt) {
        bf16x8 wfk[4];
#pragma unroll
        for (int ft = 0; ft < 4; ++ft)
            wfk[ft] = *(const bf16x8*)&W2t[(featBase + ft * 16 + lr) * D + kt * 32 + lk * 8];
        bf16x8 yf[2];
#pragma unroll
        for (int mt = 0; mt < 2; ++mt) {
            int nl = nlBase + mt * 16 + lr;
            int byteoff = nl * 256 + kt * 64 + lk * 16;
            byteoff ^= (nl & 7) << 4;
            yf[mt] = *(const bf16x8*)((char*)sy + byteoff);
        }
#pragma unroll
        for (int ft = 0; ft < 4; ++ft)
#pragma unroll
            for (int mt = 0; mt < 2; ++mt)
                acc[ft][mt] = __builtin_amdgcn_mfma_f32_16x16x32_bf16(wfk[ft], yf[mt],
                                                                      acc[ft][mt], 0, 0, 0);
    }

    // ---- bias + LeakyReLU + gproj add -> bf16 -> LDS (swizzled; after barrier) ----
    __syncthreads();  // all waves done reading sy before overwrite
#pragma unroll
    for (int ft = 0; ft < 4; ++ft) {
        int f0 = featBase + ft * 16 + lk * 4;
#pragma unroll
        for (int mt = 0; mt < 2; ++mt) {
            int nl = nlBase + mt * 16 + lr;
            int bid = batch[nIdx[mt]];
            const float4 gp = *(const float4*)&gproj[bid * D + f0];
            short4 pk;
            float v0 = acc[ft][mt][0] + sB2[f0 + 0]; v0 = (v0 > 0.f) ? v0 : NEG_SLOPE * v0; v0 += gp.x;
            float v1 = acc[ft][mt][1] + sB2[f0 + 1]; v1 = (v1 > 0.f) ? v1 : NEG_SLOPE * v1; v1 += gp.y;
            float v2 = acc[ft][mt][2] + sB2[f0 + 2]; v2 = (v2 > 0.f) ? v2 : NEG_SLOPE * v2; v2 += gp.z;
            float v3 = acc[ft][mt][3] + sB2[f0 + 3]; v3 = (v3 > 0.f) ? v3 : NEG_SLOPE * v3; v3 += gp.w;
            pk.x = f2bf(v0); pk.y = f2bf(v1); pk.z = f2bf(v2); pk.w = f2bf(v3);
            int byteoff = nl * 256 + f0 * 2;
            byteoff ^= (nl & 7) << 4;
            *(short4*)((char*)sy + byteoff) = pk;
        }
    }
    __syncthreads();

    if (!FUSE_FC) {
        // ---- coalesced copy-out: 16B/lane, contiguous 256B per node row ----
#pragma unroll
        for (int it = 0; it < 4; ++it) {
            int c = tid + it * 256;      // 0..1023
            int nl = c >> 4;
            int c8 = c & 15;
            int node = blockIdx.x * 64 + nl;
            if (node < N_NODES) {
                int byteoff = nl * 256 + c8 * 16;
                byteoff ^= (nl & 7) << 4;
                bf16x8 v = *(const bf16x8*)((char*)sy + byteoff);
                *(bf16x8*)&outb[node * D + c8 * 8] = v;
            }
        }
        return;
    }

    // ---- FUSE_FC: GEMM3 with fcW from LDS h ----
#pragma unroll
    for (int ft = 0; ft < 4; ++ft)
#pragma unroll
        for (int mt = 0; mt < 2; ++mt)
            acc[ft][mt] = (f32x4)(0.0f);

#pragma unroll
    for (int kt = 0; kt < 4; ++kt) {
        bf16x8 wfk[4];
#pragma unroll
        for (int ft = 0; ft < 4; ++ft)
            wfk[ft] = *(const bf16x8*)&Wft[(featBase + ft * 16 + lr) * D + kt * 32 + lk * 8];
        bf16x8 hf[2];
#pragma unroll
        for (int mt = 0; mt < 2; ++mt) {
            int nl = nlBase + mt * 16 + lr;
            int byteoff = nl * 256 + kt * 64 + lk * 16;
            byteoff ^= (nl & 7) << 4;
            hf[mt] = *(const bf16x8*)((char*)sy + byteoff);
        }
#pragma unroll
        for (int ft = 0; ft < 4; ++ft)
#pragma unroll
            for (int mt = 0; mt < 2; ++mt)
                acc[ft][mt] = __builtin_amdgcn_mfma_f32_16x16x32_bf16(wfk[ft], hf[mt],
                                                                      acc[ft][mt], 0, 0, 0);
    }

#pragma unroll
    for (int mt = 0; mt < 2; ++mt) {
        int node = nodeBase + mt * 16 + lr;
        if (node >= N_NODES) continue;
#pragma unroll
        for (int ft = 0; ft < 4; ++ft) {
            int f0 = featBase + ft * 16 + lk * 4;
            float4 o;
            o.x = acc[ft][mt][0] + sFC[f0 + 0];
            o.y = acc[ft][mt][1] + sFC[f0 + 1];
            o.z = acc[ft][mt][2] + sFC[f0 + 2];
            o.w = acc[ft][mt][3] + sFC[f0 + 3];
            *(float4*)&outf[node * D + f0] = o;
        }
    }
}

// ---------------- launch ----------------

extern "C" void kernel_launch(void* const* d_in, const int* in_sizes, int n_in,
                              void* d_out, int out_size, void* d_ws, size_t ws_size,
                              hipStream_t stream) {
    const float* x = (const float*)d_in[0];
    const int* ei = (const int*)d_in[1];
    const int* src = ei;
    const int* dst = ei + N_EDGES;
    const int* batch = (const int*)d_in[2];
    const float* gs = (const float*)d_in[3];
    const float* W1s = (const float*)d_in[4];
    const float* b1s = (const float*)d_in[5];
    const float* gammas = (const float*)d_in[6];
    const float* betas = (const float*)d_in[7];
    const float* means = (const float*)d_in[8];
    const float* vars = (const float*)d_in[9];
    const float* W2s = (const float*)d_in[10];
    const float* b2s = (const float*)d_in[11];
    const float* statWs = (const float*)d_in[12];
    const float* statBs = (const float*)d_in[13];
    const float* fcW = (const float*)d_in[14];
    const float* fcB = (const float*)d_in[15];
    float* out = (float*)d_out;

    char* ws = (char*)d_ws;
    auto alloc = [&](size_t bytes) {
        char* p = ws;
        ws += (bytes + 255) / 256 * 256;
        return p;
    };
    int* deg = (int*)alloc(N_NODES * sizeof(int));
    int* incl = (int*)alloc(N_NODES * sizeof(int));
    int* bsum = (int*)alloc(64 * sizeof(int));
    int* start = (int*)alloc((N_NODES + 1) * sizeof(int));
    int* cursor = (int*)alloc(N_NODES * sizeof(int));
    int* csr_src = (int*)alloc(N_EDGES * sizeof(int));
    int* bucket_cnt = (int*)alloc(NB * sizeof(int));
    int2* bucketbuf = (int2*)alloc((size_t)NB * BCAP * sizeof(int2));
    float* gproj = (float*)alloc((size_t)L_LAYERS * B_GRAPHS * D * sizeof(float));
    short* wt = (short*)alloc((size_t)7 * D * D * sizeof(short));
    short* xb = (short*)alloc((size_t)N_NODES * D * sizeof(short));
    short* hb = (short*)alloc((size_t)N_NODES * D * sizeof(short));
    short* m_bf = (short*)alloc((size_t)N_NODES * D * sizeof(short));

    const int nscan = (N_NODES + 2047) / 2048;

    // CSR build, bucketed
    zero_n_kernel<<<1, 256, 0, stream>>>(bucket_cnt, NB);
    bucketA_kernel<<<N_EDGES / EPB, 256, 0, stream>>>(src, dst, bucket_cnt, bucketbuf);
    bucketB1_kernel<<<NB, 256, 0, stream>>>(bucket_cnt, bucketbuf, deg);
    scan1_kernel<<<nscan, 256, 0, stream>>>(deg, incl, bsum);
    scan2_kernel<<<1, 64, 0, stream>>>(bsum, nscan);
    scan3_kernel<<<(N_NODES + 255) / 256, 256, 0, stream>>>(deg, incl, bsum, start, cursor);
    bucketB2_kernel<<<NB, 256, 0, stream>>>(bucket_cnt, bucketbuf, cursor, csr_src);

    gproj_kernel<<<dim3(B_GRAPHS, L_LAYERS), D, 0, stream>>>(gs, statWs, statBs, gproj);
    wconv_kernel<<<dim3(64, 7), 256, 0, stream>>>(W1s, W2s, fcW, wt);
    xconv_kernel<<<(N_NODES * D / 8 + 255) / 256, 256, 0, stream>>>(x, xb);

    const int agg_blocks = N_NODES / 16;         // 6250
    const int mlp_blocks = (N_NODES + 63) / 64;  // 1563

    // layer 0
    agg_kernel<<<agg_blocks, 256, 0, stream>>>(xb, start, csr_src, m_bf);
    mlp_mfma_kernel<false><<<mlp_blocks, 256, 0, stream>>>(
        m_bf, wt + 0 * D * D, b1s + 0 * D, gammas + 0 * D, betas + 0 * D, means + 0 * D,
        vars + 0 * D, wt + 3 * D * D, b2s + 0 * D, gproj + 0 * B_GRAPHS * D, batch,
        nullptr, nullptr, nullptr, hb);
    // layer 1
    agg_kernel<<<agg_blocks, 256, 0, stream>>>(hb, start, csr_src, m_bf);
    mlp_mfma_kernel<false><<<mlp_blocks, 256, 0, stream>>>(
        m_bf, wt + 1 * D * D, b1s + 1 * D, gammas + 1 * D, betas + 1 * D, means + 1 * D,
        vars + 1 * D, wt + 4 * D * D, b2s + 1 * D, gproj + 1 * B_GRAPHS * D, batch,
        nullptr, nullptr, nullptr, hb);
    // layer 2
    agg_kernel<<<agg_blocks, 256, 0, stream>>>(hb, start, csr_src, m_bf);
    mlp_mfma_kernel<true><<<mlp_blocks, 256, 0, stream>>>(
        m_bf, wt + 2 * D * D, b1s + 2 * D, gammas + 2 * D, betas + 2 * D, means + 2 * D,
        vars + 2 * D, wt + 5 * D * D, b2s + 2 * D, gproj + 2 * B_GRAPHS * D, batch,
        wt + 6 * D * D, fcB, out, nullptr);
}